// Round 4
// baseline (102.015 us; speedup 1.0000x reference)
//
#include <hip/hip_runtime.h>
#include <stdint.h>

// Bahdanau attention: B=64, T=2048, D=256, U=256, all fp32 in/out.
// out = [context (B*D) | attn (B*T)] flat fp32.
#define Bq 64
#define Tq 2048
#define Dq 256
#define Uq 256

// A LDS layout (per buffer): [k-octet 0..3][row 0..127][8 bf16 = 16B], +16B pad/region
#define AST 2064              // bytes per octet region (128*16 + 16)
#define APL (4 * AST)         // one plane (hi or lo) = 8256 B
#define ABUF (2 * APL)        // hi+lo = 16512 B

typedef __bf16 bf16x8 __attribute__((ext_vector_type(8)));
typedef float f32x4 __attribute__((ext_vector_type(4)));

// split fp32 into truncated-bf16 hi + bf16(lo) residual. a = hi + lo + O(2^-16 |a|)
__device__ inline void split2(float a, unsigned short& h, unsigned short& l) {
  unsigned bits = __float_as_uint(a);
  h = (unsigned short)(bits >> 16);
  float hf = __uint_as_float(bits & 0xffff0000u);
  l = (unsigned short)(__float_as_uint(a - hf) >> 16);
}

// tanh(x) = 1 - 2/(exp(2x)+1). ~6 VALU ops, saturates correctly.
__device__ inline float fast_tanh(float x) {
  float e = __expf(2.0f * x);
  return 1.0f - 2.0f * __builtin_amdgcn_rcpf(e + 1.0f);
}

// K0: split w1 [U][D] fp32 -> bf16 hi/lo planes, stored OCTET-MAJOR:
// plane[(k>>3)*U*8 + u*8 + (k&7)]
__global__ void k0_split(const float* __restrict__ w1,
                         unsigned short* __restrict__ hi,
                         unsigned short* __restrict__ lo) {
  int idx = blockIdx.x * 256 + threadIdx.x;
  int i = idx * 4;
  int u = i >> 8;
  int k = i & 255;
  float4 v = *reinterpret_cast<const float4*>(&w1[i]);
  ushort4 h, l;
  split2(v.x, h.x, l.x);
  split2(v.y, h.y, l.y);
  split2(v.z, h.z, l.z);
  split2(v.w, h.w, l.w);
  int dst = (k >> 3) * (Uq * 8) + u * 8 + (k & 7);
  *reinterpret_cast<ushort4*>(&hi[dst]) = h;
  *reinterpret_cast<ushort4*>(&lo[dst]) = l;
}

// K1: comb[b][u] = dot(hidden[b], w2_w[u]) + w2_b[u] + w1_b[u]
__global__ void k1_comb(const float* __restrict__ hidden,
                        const float* __restrict__ w2_w,
                        const float* __restrict__ w2_b,
                        const float* __restrict__ w1_b,
                        float* __restrict__ comb) {
  int b = blockIdx.x;
  int wave = threadIdx.x >> 6;
  int lane = threadIdx.x & 63;
  int u = blockIdx.y * 4 + wave;
  const float* h = hidden + b * Dq;
  const float* w = w2_w + u * Dq;
  float sum = 0.f;
#pragma unroll
  for (int i = 0; i < Dq; i += 64) sum += h[lane + i] * w[lane + i];
#pragma unroll
  for (int m = 32; m >= 1; m >>= 1) sum += __shfl_xor(sum, m, 64);
  if (lane == 0) comb[b * Uq + u] = sum + w2_b[u] + w1_b[u];
}

// K2: score[b][t] = v_b + sum_u v_w[u] * tanh( feat[b,t,:]·w1_w[u,:] + comb[b][u] )
// MFMA 16x16x32 bf16, split precision (3 planes). 512 thr = 8 waves.
// Block tile 128t x 256u; wave (wr = w>>2, wc = w&3) owns 64t x 64u.
// A (features hi/lo) staged in double-buffered LDS; B (w1 hi/lo) fragments
// loaded straight from L2-resident octet-major global planes into VGPRs.
__global__ __launch_bounds__(512) void k2_score(
    const float* __restrict__ feat, const unsigned short* __restrict__ w1hi,
    const unsigned short* __restrict__ w1lo, const float* __restrict__ comb,
    const float* __restrict__ v_w, const float* __restrict__ v_b,
    float* __restrict__ score) {
  __shared__ char cA[2 * ABUF];       // double-buffered A (hi plane, lo plane)
  __shared__ float scp[8 * 64];
  const int b = blockIdx.y;
  const int t0 = blockIdx.x * 128;
  const int tid = threadIdx.x;
  const int w = tid >> 6;
  const int l = tid & 63;
  const int fr = l & 15;
  const int g = l >> 4;
  const int wr = w >> 2;
  const int wc = w & 3;

  // A staging role: thread -> (row, octet)
  const int srow = tid >> 2;
  const int soct = tid & 3;
  const float* sfeat = feat + ((size_t)(b * Tq + t0 + srow)) * Dq + soct * 8;
  char* sdst = cA + soct * AST + srow * 16;

  f32x4 acc[4][4] = {};

  for (int kc = 0; kc < Dq; kc += 32) {
    char* buf = cA + ((kc >> 5) & 1) * ABUF;
    // ---- stage A chunk (this thread's octet of one row) ----
    {
      float4 v0 = *reinterpret_cast<const float4*>(sfeat + kc);
      float4 v1 = *reinterpret_cast<const float4*>(sfeat + kc + 4);
      float f[8] = {v0.x, v0.y, v0.z, v0.w, v1.x, v1.y, v1.z, v1.w};
      unsigned short h[8], lo8[8];
#pragma unroll
      for (int j = 0; j < 8; ++j) split2(f[j], h[j], lo8[j]);
      uint4 H, L;
      H.x = h[0] | (h[1] << 16);  H.y = h[2] | (h[3] << 16);
      H.z = h[4] | (h[5] << 16);  H.w = h[6] | (h[7] << 16);
      L.x = lo8[0] | (lo8[1] << 16); L.y = lo8[2] | (lo8[3] << 16);
      L.z = lo8[4] | (lo8[5] << 16); L.w = lo8[6] | (lo8[7] << 16);
      char* d = sdst + ((kc >> 5) & 1) * ABUF;
      *reinterpret_cast<uint4*>(d) = H;
      *reinterpret_cast<uint4*>(d + APL) = L;
    }
    // ---- B fragments straight from global (octet-major, L2-resident) ----
    bf16x8 bh[4], bl[4];
    {
      const int ko = (kc >> 3) + g;  // this lane's k-octet
#pragma unroll
      for (int nf = 0; nf < 4; ++nf) {
        int u = wc * 64 + nf * 16 + fr;
        size_t off = (size_t)ko * (Uq * 8) + u * 8;
        bh[nf] = *reinterpret_cast<const bf16x8*>(&w1hi[off]);
        bl[nf] = *reinterpret_cast<const bf16x8*>(&w1lo[off]);
      }
    }
    __syncthreads();
    // ---- A fragments from LDS ----
    bf16x8 ah[4], al[4];
#pragma unroll
    for (int mf = 0; mf < 4; ++mf) {
      int aoff = g * AST + (wr * 64 + mf * 16 + fr) * 16;
      ah[mf] = *reinterpret_cast<const bf16x8*>(buf + aoff);
      al[mf] = *reinterpret_cast<const bf16x8*>(buf + APL + aoff);
    }
    // ---- 3-plane MFMA ----
#pragma unroll
    for (int mf = 0; mf < 4; ++mf) {
#pragma unroll
      for (int nf = 0; nf < 4; ++nf) {
        acc[mf][nf] = __builtin_amdgcn_mfma_f32_16x16x32_bf16(
            ah[mf], bh[nf], acc[mf][nf], 0, 0, 0);
        acc[mf][nf] = __builtin_amdgcn_mfma_f32_16x16x32_bf16(
            ah[mf], bl[nf], acc[mf][nf], 0, 0, 0);
        acc[mf][nf] = __builtin_amdgcn_mfma_f32_16x16x32_bf16(
            al[mf], bh[nf], acc[mf][nf], 0, 0, 0);
      }
    }
  }

  // epilogue: tanh + v-dot. acc[mf][nf][r] is (t_local = wr*64 + mf*16 + g*4 + r,
  // u = wc*64 + nf*16 + fr)
  float cb[4], vw4[4];
#pragma unroll
  for (int nf = 0; nf < 4; ++nf) {
    int u = wc * 64 + nf * 16 + fr;
    cb[nf] = comb[b * Uq + u];
    vw4[nf] = v_w[u];
  }
  float sc[4][4];
#pragma unroll
  for (int mf = 0; mf < 4; ++mf)
#pragma unroll
    for (int r = 0; r < 4; ++r) sc[mf][r] = 0.f;
#pragma unroll
  for (int mf = 0; mf < 4; ++mf)
#pragma unroll
    for (int nf = 0; nf < 4; ++nf)
#pragma unroll
      for (int r = 0; r < 4; ++r)
        sc[mf][r] += vw4[nf] * fast_tanh(acc[mf][nf][r] + cb[nf]);
  // reduce over the 16 fr lanes (u within this wave's 64)
#pragma unroll
  for (int m = 1; m < 16; m <<= 1)
#pragma unroll
    for (int mf = 0; mf < 4; ++mf)
#pragma unroll
      for (int r = 0; r < 4; ++r) sc[mf][r] += __shfl_xor(sc[mf][r], m, 16);
  if (fr == 0) {
#pragma unroll
    for (int mf = 0; mf < 4; ++mf)
#pragma unroll
      for (int r = 0; r < 4; ++r)
        scp[w * 64 + mf * 16 + g * 4 + r] = sc[mf][r];
  }
  __syncthreads();
  if (tid < 128) {
    int wr2 = tid >> 6;
    int tl = tid & 63;
    float v = scp[(wr2 * 4 + 0) * 64 + tl] + scp[(wr2 * 4 + 1) * 64 + tl] +
              scp[(wr2 * 4 + 2) * 64 + tl] + scp[(wr2 * 4 + 3) * 64 + tl];
    score[b * Tq + t0 + tid] = v + v_b[0];
  }
}

// K3: softmax over T per batch, in place. 256 threads, 8 values each.
__global__ void k3_softmax(float* __restrict__ s) {
  int b = blockIdx.x;
  int tid = threadIdx.x;
  const int base = b * Tq;
  float v[8];
  float m = -1e30f;
#pragma unroll
  for (int i = 0; i < 8; ++i) {
    v[i] = s[base + tid + 256 * i];
    m = fmaxf(m, v[i]);
  }
#pragma unroll
  for (int mk = 32; mk >= 1; mk >>= 1) m = fmaxf(m, __shfl_xor(m, mk, 64));
  __shared__ float red[4];
  int wv = tid >> 6, ln = tid & 63;
  if (ln == 0) red[wv] = m;
  __syncthreads();
  m = fmaxf(fmaxf(red[0], red[1]), fmaxf(red[2], red[3]));
  __syncthreads();
  float sum = 0.f;
#pragma unroll
  for (int i = 0; i < 8; ++i) {
    v[i] = __expf(v[i] - m);
    sum += v[i];
  }
#pragma unroll
  for (int mk = 32; mk >= 1; mk >>= 1) sum += __shfl_xor(sum, mk, 64);
  if (ln == 0) red[wv] = sum;
  __syncthreads();
  sum = red[0] + red[1] + red[2] + red[3];
  float inv = 1.f / sum;
#pragma unroll
  for (int i = 0; i < 8; ++i) s[base + tid + 256 * i] = v[i] * inv;
}

// K4a: partial context over a 256-t slice
__global__ void k4_partial(const float* __restrict__ feat,
                           const float* __restrict__ attn,
                           float* __restrict__ part) {
  int b = blockIdx.x;
  int ts = blockIdx.y;
  int d = threadIdx.x;
  const int t0 = ts * 256;
  const float* f = feat + ((size_t)(b * Tq + t0)) * Dq + d;
  const float* a = attn + b * Tq + t0;
  float acc = 0.f;
#pragma unroll 8
  for (int t = 0; t < 256; ++t) acc += a[t] * f[(size_t)t * Dq];
  part[(b * 8 + ts) * Dq + d] = acc;
}

// K4b: reduce the 8 partials
__global__ void k4_reduce(const float* __restrict__ part,
                          float* __restrict__ ctx) {
  int b = blockIdx.x;
  int d = threadIdx.x;
  float s = 0.f;
#pragma unroll
  for (int ts = 0; ts < 8; ++ts) s += part[(b * 8 + ts) * Dq + d];
  ctx[b * Dq + d] = s;
}

extern "C" void kernel_launch(void* const* d_in, const int* in_sizes, int n_in,
                              void* d_out, int out_size, void* d_ws,
                              size_t ws_size, hipStream_t stream) {
  const float* feat   = (const float*)d_in[0];
  const float* hidden = (const float*)d_in[1];
  const float* w1_w   = (const float*)d_in[2];
  const float* w1_b   = (const float*)d_in[3];
  const float* w2_w   = (const float*)d_in[4];
  const float* w2_b   = (const float*)d_in[5];
  const float* v_w    = (const float*)d_in[6];
  const float* v_b    = (const float*)d_in[7];

  float* ctx  = (float*)d_out;             // [B][D]
  float* attn = ctx + Bq * Dq;             // [B][T] (score -> softmax in place)
  float* comb = (float*)d_ws;              // [B][U]              64 KB
  float* part = comb + Bq * Uq;            // [B][8][D]           512 KB
  unsigned short* w1hi = (unsigned short*)(part + Bq * 8 * Dq);  // 128 KB
  unsigned short* w1lo = w1hi + Uq * Dq;                          // 128 KB

  k0_split<<<Uq * Dq / 1024, 256, 0, stream>>>(w1_w, w1hi, w1lo);
  k1_comb<<<dim3(Bq, Uq / 4), 256, 0, stream>>>(hidden, w2_w, w2_b, w1_b, comb);
  k2_score<<<dim3(Tq / 128, Bq), 512, 0, stream>>>(feat, w1hi, w1lo, comb, v_w,
                                                   v_b, attn);
  k3_softmax<<<Bq, 256, 0, stream>>>(attn);
  k4_partial<<<dim3(Bq, 8), 256, 0, stream>>>(feat, attn, part);
  k4_reduce<<<Bq, 256, 0, stream>>>(part, ctx);
}

// Round 5
// 91.709 us; speedup vs baseline: 1.1124x; 1.1124x over previous
//
#include <hip/hip_runtime.h>
#include <stdint.h>

// Bahdanau attention: B=64, T=2048, D=256, U=256, all fp32 in/out.
// out = [context (B*D) | attn (B*T)] flat fp32.
#define Bq 64
#define Tq 2048
#define Dq 256
#define Uq 256

// A LDS layout (per buffer): [k-octet 0..3][row 0..63][8 bf16 = 16B], +16B pad/region
#define AST 1040              // bytes per octet region (64*16 + 16)
#define APL (4 * AST)         // one plane (hi or lo) = 4160 B
#define ABUF (2 * APL)        // hi+lo = 8320 B

typedef __bf16 bf16x8 __attribute__((ext_vector_type(8)));
typedef float f32x4 __attribute__((ext_vector_type(4)));

// split fp32 into truncated-bf16 hi + bf16(lo) residual. a = hi + lo + O(2^-16 |a|)
__device__ inline void split2(float a, unsigned short& h, unsigned short& l) {
  unsigned bits = __float_as_uint(a);
  h = (unsigned short)(bits >> 16);
  float hf = __uint_as_float(bits & 0xffff0000u);
  l = (unsigned short)(__float_as_uint(a - hf) >> 16);
}

// tanh(x) = 1 - 2/(exp(2x)+1). ~6 VALU ops, saturates correctly.
__device__ inline float fast_tanh(float x) {
  float e = __expf(2.0f * x);
  return 1.0f - 2.0f * __builtin_amdgcn_rcpf(e + 1.0f);
}

// K0: split w1 [U][D] fp32 -> bf16 hi/lo planes, stored OCTET-MAJOR:
// plane[(k>>3)*U*8 + u*8 + (k&7)]
__global__ void k0_split(const float* __restrict__ w1,
                         unsigned short* __restrict__ hi,
                         unsigned short* __restrict__ lo) {
  int idx = blockIdx.x * 256 + threadIdx.x;
  int i = idx * 4;
  int u = i >> 8;
  int k = i & 255;
  float4 v = *reinterpret_cast<const float4*>(&w1[i]);
  ushort4 h, l;
  split2(v.x, h.x, l.x);
  split2(v.y, h.y, l.y);
  split2(v.z, h.z, l.z);
  split2(v.w, h.w, l.w);
  int dst = (k >> 3) * (Uq * 8) + u * 8 + (k & 7);
  *reinterpret_cast<ushort4*>(&hi[dst]) = h;
  *reinterpret_cast<ushort4*>(&lo[dst]) = l;
}

// K1: comb[b][u] = dot(hidden[b], w2_w[u]) + w2_b[u] + w1_b[u]
__global__ void k1_comb(const float* __restrict__ hidden,
                        const float* __restrict__ w2_w,
                        const float* __restrict__ w2_b,
                        const float* __restrict__ w1_b,
                        float* __restrict__ comb) {
  int b = blockIdx.x;
  int wave = threadIdx.x >> 6;
  int lane = threadIdx.x & 63;
  int u = blockIdx.y * 4 + wave;
  const float* h = hidden + b * Dq;
  const float* w = w2_w + u * Dq;
  float sum = 0.f;
#pragma unroll
  for (int i = 0; i < Dq; i += 64) sum += h[lane + i] * w[lane + i];
#pragma unroll
  for (int m = 32; m >= 1; m >>= 1) sum += __shfl_xor(sum, m, 64);
  if (lane == 0) comb[b * Uq + u] = sum + w2_b[u] + w1_b[u];
}

// K2: score[b][t] = v_b + sum_u v_w[u] * tanh( feat[b,t,:]·w1_w[u,:] + comb[b][u] )
// MFMA 16x16x32 bf16, split precision (3 planes). 256 thr = 4 waves.
// Block tile 64t x 256u; wave (wr=w>>1, wc=w&1) owns 32t x 128u.
// A (features hi/lo) in double-buffered LDS with 1-chunk-ahead register
// prefetch; B (w1 hi/lo) fragments straight from L1/L2-resident global.
__global__ __launch_bounds__(256) void k2_score(
    const float* __restrict__ feat, const unsigned short* __restrict__ w1hi,
    const unsigned short* __restrict__ w1lo, const float* __restrict__ comb,
    const float* __restrict__ v_w, const float* __restrict__ v_b,
    float* __restrict__ score) {
  __shared__ char cA[2 * ABUF];
  __shared__ float scp[4 * 32];
  const int b = blockIdx.y;
  const int t0 = blockIdx.x * 64;
  const int tid = threadIdx.x;
  const int w = tid >> 6;
  const int l = tid & 63;
  const int fr = l & 15;
  const int g = l >> 4;
  const int wr = w >> 1;
  const int wc = w & 1;

  // A staging role: thread -> (row, octet); one 8-float octet per chunk.
  const int srow = tid >> 2;
  const int soct = tid & 3;
  const float* sfeat = feat + ((size_t)(b * Tq + t0 + srow)) * Dq + soct * 8;
  char* sdst0 = cA + soct * AST + srow * 16;

  f32x4 acc[2][8] = {};

  // prologue: prefetch chunk 0 features into regs
  float4 pv0 = *reinterpret_cast<const float4*>(sfeat);
  float4 pv1 = *reinterpret_cast<const float4*>(sfeat + 4);

  for (int c = 0; c < 8; ++c) {
    const int kc = c * 32;
    char* buf = cA + (c & 1) * ABUF;
    // ---- issue B loads for this chunk (L1-resident; consumed after barrier)
    bf16x8 bh[8], bl[8];
    const int ko = (kc >> 3) + g;
#pragma unroll
    for (int nf = 0; nf < 8; ++nf) {
      int u = wc * 128 + nf * 16 + fr;
      size_t off = (size_t)ko * (Uq * 8) + u * 8;
      bh[nf] = *reinterpret_cast<const bf16x8*>(&w1hi[off]);
      bl[nf] = *reinterpret_cast<const bf16x8*>(&w1lo[off]);
    }
    // ---- split current chunk's prefetched A regs -> LDS
    {
      float f[8] = {pv0.x, pv0.y, pv0.z, pv0.w, pv1.x, pv1.y, pv1.z, pv1.w};
      unsigned short h[8], lo8[8];
#pragma unroll
      for (int j = 0; j < 8; ++j) split2(f[j], h[j], lo8[j]);
      uint4 H, L;
      H.x = h[0] | (h[1] << 16);    H.y = h[2] | (h[3] << 16);
      H.z = h[4] | (h[5] << 16);    H.w = h[6] | (h[7] << 16);
      L.x = lo8[0] | (lo8[1] << 16); L.y = lo8[2] | (lo8[3] << 16);
      L.z = lo8[4] | (lo8[5] << 16); L.w = lo8[6] | (lo8[7] << 16);
      char* d = sdst0 + (c & 1) * ABUF;
      *reinterpret_cast<uint4*>(d) = H;
      *reinterpret_cast<uint4*>(d + APL) = L;
    }
    // ---- prefetch next chunk's features (wraps harmlessly on last iter)
    {
      const int kn = (kc + 32) & 255;
      pv0 = *reinterpret_cast<const float4*>(sfeat + kn);
      pv1 = *reinterpret_cast<const float4*>(sfeat + kn + 4);
    }
    __syncthreads();
    // ---- A fragments from LDS
    bf16x8 ah[2], al[2];
#pragma unroll
    for (int mf = 0; mf < 2; ++mf) {
      int aoff = g * AST + (wr * 32 + mf * 16 + fr) * 16;
      ah[mf] = *reinterpret_cast<const bf16x8*>(buf + aoff);
      al[mf] = *reinterpret_cast<const bf16x8*>(buf + APL + aoff);
    }
    // ---- 3-plane MFMA
#pragma unroll
    for (int mf = 0; mf < 2; ++mf) {
#pragma unroll
      for (int nf = 0; nf < 8; ++nf) {
        acc[mf][nf] = __builtin_amdgcn_mfma_f32_16x16x32_bf16(
            ah[mf], bh[nf], acc[mf][nf], 0, 0, 0);
        acc[mf][nf] = __builtin_amdgcn_mfma_f32_16x16x32_bf16(
            ah[mf], bl[nf], acc[mf][nf], 0, 0, 0);
        acc[mf][nf] = __builtin_amdgcn_mfma_f32_16x16x32_bf16(
            al[mf], bh[nf], acc[mf][nf], 0, 0, 0);
      }
    }
  }

  // epilogue: tanh + v-dot. acc[mf][nf][r] is (t_local = wr*32 + mf*16 + g*4 + r,
  // u = wc*128 + nf*16 + fr)
  float cb[8], vw8[8];
#pragma unroll
  for (int nf = 0; nf < 8; ++nf) {
    int u = wc * 128 + nf * 16 + fr;
    cb[nf] = comb[b * Uq + u];
    vw8[nf] = v_w[u];
  }
  float sc[2][4];
#pragma unroll
  for (int mf = 0; mf < 2; ++mf)
#pragma unroll
    for (int r = 0; r < 4; ++r) sc[mf][r] = 0.f;
#pragma unroll
  for (int mf = 0; mf < 2; ++mf)
#pragma unroll
    for (int nf = 0; nf < 8; ++nf)
#pragma unroll
      for (int r = 0; r < 4; ++r)
        sc[mf][r] += vw8[nf] * fast_tanh(acc[mf][nf][r] + cb[nf]);
  // reduce over the 16 fr lanes (u within this wave's 128)
#pragma unroll
  for (int m = 1; m < 16; m <<= 1)
#pragma unroll
    for (int mf = 0; mf < 2; ++mf)
#pragma unroll
      for (int r = 0; r < 4; ++r) sc[mf][r] += __shfl_xor(sc[mf][r], m, 16);
  if (fr == 0) {
#pragma unroll
    for (int mf = 0; mf < 2; ++mf)
#pragma unroll
      for (int r = 0; r < 4; ++r)
        scp[w * 32 + mf * 16 + g * 4 + r] = sc[mf][r];
  }
  __syncthreads();
  if (tid < 64) {
    int wr2 = tid >> 5;
    int idx = tid & 31;
    float v = scp[(wr2 * 2 + 0) * 32 + idx] + scp[(wr2 * 2 + 1) * 32 + idx];
    score[b * Tq + t0 + tid] = v + v_b[0];
  }
}

// K3: softmax over T per batch, in place. 256 threads, 8 values each.
__global__ void k3_softmax(float* __restrict__ s) {
  int b = blockIdx.x;
  int tid = threadIdx.x;
  const int base = b * Tq;
  float v[8];
  float m = -1e30f;
#pragma unroll
  for (int i = 0; i < 8; ++i) {
    v[i] = s[base + tid + 256 * i];
    m = fmaxf(m, v[i]);
  }
#pragma unroll
  for (int mk = 32; mk >= 1; mk >>= 1) m = fmaxf(m, __shfl_xor(m, mk, 64));
  __shared__ float red[4];
  int wv = tid >> 6, ln = tid & 63;
  if (ln == 0) red[wv] = m;
  __syncthreads();
  m = fmaxf(fmaxf(red[0], red[1]), fmaxf(red[2], red[3]));
  __syncthreads();
  float sum = 0.f;
#pragma unroll
  for (int i = 0; i < 8; ++i) {
    v[i] = __expf(v[i] - m);
    sum += v[i];
  }
#pragma unroll
  for (int mk = 32; mk >= 1; mk >>= 1) sum += __shfl_xor(sum, mk, 64);
  if (ln == 0) red[wv] = sum;
  __syncthreads();
  sum = red[0] + red[1] + red[2] + red[3];
  float inv = 1.f / sum;
#pragma unroll
  for (int i = 0; i < 8; ++i) s[base + tid + 256 * i] = v[i] * inv;
}

// K4a: partial context over a 256-t slice
__global__ void k4_partial(const float* __restrict__ feat,
                           const float* __restrict__ attn,
                           float* __restrict__ part) {
  int b = blockIdx.x;
  int ts = blockIdx.y;
  int d = threadIdx.x;
  const int t0 = ts * 256;
  const float* f = feat + ((size_t)(b * Tq + t0)) * Dq + d;
  const float* a = attn + b * Tq + t0;
  float acc = 0.f;
#pragma unroll 8
  for (int t = 0; t < 256; ++t) acc += a[t] * f[(size_t)t * Dq];
  part[(b * 8 + ts) * Dq + d] = acc;
}

// K4b: reduce the 8 partials
__global__ void k4_reduce(const float* __restrict__ part,
                          float* __restrict__ ctx) {
  int b = blockIdx.x;
  int d = threadIdx.x;
  float s = 0.f;
#pragma unroll
  for (int ts = 0; ts < 8; ++ts) s += part[(b * 8 + ts) * Dq + d];
  ctx[b * Dq + d] = s;
}

extern "C" void kernel_launch(void* const* d_in, const int* in_sizes, int n_in,
                              void* d_out, int out_size, void* d_ws,
                              size_t ws_size, hipStream_t stream) {
  const float* feat   = (const float*)d_in[0];
  const float* hidden = (const float*)d_in[1];
  const float* w1_w   = (const float*)d_in[2];
  const float* w1_b   = (const float*)d_in[3];
  const float* w2_w   = (const float*)d_in[4];
  const float* w2_b   = (const float*)d_in[5];
  const float* v_w    = (const float*)d_in[6];
  const float* v_b    = (const float*)d_in[7];

  float* ctx  = (float*)d_out;             // [B][D]
  float* attn = ctx + Bq * Dq;             // [B][T] (score -> softmax in place)
  float* comb = (float*)d_ws;              // [B][U]              64 KB
  float* part = comb + Bq * Uq;            // [B][8][D]           512 KB
  unsigned short* w1hi = (unsigned short*)(part + Bq * 8 * Dq);  // 128 KB
  unsigned short* w1lo = w1hi + Uq * Dq;                          // 128 KB

  k0_split<<<Uq * Dq / 1024, 256, 0, stream>>>(w1_w, w1hi, w1lo);
  k1_comb<<<dim3(Bq, Uq / 4), 256, 0, stream>>>(hidden, w2_w, w2_b, w1_b, comb);
  k2_score<<<dim3(Tq / 64, Bq), 256, 0, stream>>>(feat, w1hi, w1lo, comb, v_w,
                                                  v_b, attn);
  k3_softmax<<<Bq, 256, 0, stream>>>(attn);
  k4_partial<<<dim3(Bq, 8), 256, 0, stream>>>(feat, attn, part);
  k4_reduce<<<Bq, 256, 0, stream>>>(part, ctx);
}